// Round 2
// 265.414 us; speedup vs baseline: 1.1890x; 1.1890x over previous
//
#include <hip/hip_runtime.h>
#include <stdint.h>

#define NB 32
#define CC 64
#define HH 112
#define WW 112
#define HW (HH * WW)            // 12544
#define NHW (NB * HW)           // 401408

// ---------------- kernel 1: binarize weights -> bits + scale; zero stat accumulators
__global__ void wpack_kernel(const float* __restrict__ wflat,
                             uint64_t* __restrict__ wbits,
                             float* __restrict__ wscale,
                             int* __restrict__ ch_sum,
                             unsigned long long* __restrict__ ch_sumsq) {
    int o = blockIdx.x;      // 64 blocks, one per output channel
    int i = threadIdx.x;     // 64 threads = input channel (lane id)
    const float* wp = wflat + (size_t)(o * 64 + i) * 9;
    float w[9];
    float asum = 0.f;
#pragma unroll
    for (int t = 0; t < 9; t++) { w[t] = wp[t]; asum += fabsf(w[t]); }
#pragma unroll
    for (int s = 32; s > 0; s >>= 1) asum += __shfl_xor(asum, s, 64);
    float scale = asum * (1.0f / 576.0f);
    uint64_t b[9];
#pragma unroll
    for (int t = 0; t < 9; t++) b[t] = __ballot(w[t] >= 0.0f);  // bit i = sign(+) of in-channel i
    if (i == 0) {
#pragma unroll
        for (int t = 0; t < 9; t++) wbits[o * 9 + t] = b[t];
        wscale[o] = scale;
        ch_sum[o] = 0;
        ch_sumsq[o] = 0ull;
    }
}

// ---------------- kernel 2: pack sign(x) bits per pixel over 64 channels (float2-vectorized)
__global__ __launch_bounds__(256) void xpack2_kernel(const float* __restrict__ x,
                                                     uint64_t* __restrict__ bits) {
    int p2 = blockIdx.x * 256 + threadIdx.x;   // pixel-pair index, < NHW/2 exactly
    int n = p2 / (HW / 2);
    int r2 = p2 - n * (HW / 2);
    const float2* xp = (const float2*)(x + (size_t)n * CC * HW) + r2;
    uint64_t b0 = 0, b1 = 0;
#pragma unroll 8
    for (int c = 0; c < 64; c++) {
        float2 v = xp[(size_t)c * (HW / 2)];
        b0 |= (uint64_t)(v.x > 0.0f) << c;
        b1 |= (uint64_t)(v.y > 0.0f) << c;
    }
    ulonglong2 pr;
    pr.x = b0; pr.y = b1;
    *((ulonglong2*)(bits + (size_t)n * HW) + r2) = pr;
}

// ---- helpers for the stats kernel (lane = output channel) ----
struct WRegs {
    uint64_t w[9];
    int corrMid, dL, dR;
};

__device__ __forceinline__ void load_wregs(WRegs& W, const uint64_t* __restrict__ wbits,
                                           int lane, int h) {
    int tc[9];
#pragma unroll
    for (int t = 0; t < 9; t++) {
        W.w[t] = wbits[lane * 9 + t];
        tc[t] = 64 - 2 * (int)__builtin_popcountll(W.w[t]);
    }
    W.corrMid = 0;
    int oL = 0, oR = 0;
    if (h == 0)      { W.corrMid = tc[0] + tc[1] + tc[2]; oL = tc[0]; oR = tc[2]; }
    if (h == HH - 1) { W.corrMid = tc[6] + tc[7] + tc[8]; oL = tc[6]; oR = tc[8]; }
    W.dL = tc[0] + tc[3] + tc[6] - oL;
    W.dR = tc[2] + tc[5] + tc[8] - oR;
}

__device__ __forceinline__ int conv_px(const uint64_t l[3], const uint64_t m[3],
                                       const uint64_t r[3], const WRegs& W) {
    int pc = 0;
#pragma unroll
    for (int rr = 0; rr < 3; rr++) {
        pc += (int)__builtin_popcountll(l[rr] ^ W.w[rr * 3 + 0]);
        pc += (int)__builtin_popcountll(m[rr] ^ W.w[rr * 3 + 1]);
        pc += (int)__builtin_popcountll(r[rr] ^ W.w[rr * 3 + 2]);
    }
    return 576 - 2 * pc - W.corrMid;
}

// ---------------- kernel 3: conv + per-channel sum / sumsq (integer exact)
// wave = one HALF image row (56 px), lane = output channel. 7168 waves total.
__global__ __launch_bounds__(256) void stats3_kernel(const uint64_t* __restrict__ bits,
                                                     const uint64_t* __restrict__ wbits,
                                                     int* __restrict__ ch_sum,
                                                     unsigned long long* __restrict__ ch_sumsq) {
    __shared__ uint64_t rowbuf[4][3][58];
    __shared__ int redS[4][64];
    __shared__ int redQ[4][64];
    int tid = threadIdx.x;
    int wave = tid >> 6, lane = tid & 63;
    int Wid = blockIdx.x * 4 + wave;                  // < 7168 exact
    int n = __builtin_amdgcn_readfirstlane(Wid / 224);
    int rem = Wid - n * 224;
    int h = __builtin_amdgcn_readfirstlane(rem >> 1);
    int c0 = __builtin_amdgcn_readfirstlane((rem & 1) * 56);
    const uint64_t* bp = bits + (size_t)n * HW;

    // stage 3 rows x 58 cols (c0-1 .. c0+56), zero padded
    for (int e = lane; e < 3 * 58; e += 64) {
        int t = e / 58, c = e - t * 58;
        int hh = h - 1 + t, ww = c0 - 1 + c;
        uint64_t v = 0;
        if (hh >= 0 && hh < HH && ww >= 0 && ww < WW) v = bp[hh * WW + ww];
        rowbuf[wave][t][c] = v;
    }
    WRegs W;
    load_wregs(W, wbits, lane, h);
    __syncthreads();

    const uint64_t(*rb)[58] = rowbuf[wave];
    int s1 = 0, s2 = 0;
    uint64_t win[3][3];
    for (int j0 = 0; j0 < 56; j0 += 14) {
#pragma unroll
        for (int rr = 0; rr < 3; rr++) { win[0][rr] = rb[rr][j0]; win[1][rr] = rb[rr][j0 + 1]; }
#pragma unroll
        for (int j = 0; j < 14; j++) {
#pragma unroll
            for (int rr = 0; rr < 3; rr++) win[(j + 2) % 3][rr] = rb[rr][j0 + j + 2];
            int S = conv_px(win[j % 3], win[(j + 1) % 3], win[(j + 2) % 3], W);
            int wpx = c0 + j0 + j;
            if (wpx == 0) S -= W.dL;
            if (wpx == WW - 1) S -= W.dR;
            s1 += S;
            s2 += S * S;
        }
    }
    redS[wave][lane] = s1;
    redQ[wave][lane] = s2;
    __syncthreads();
    if (tid < 64) {
        int t1 = redS[0][tid] + redS[1][tid] + redS[2][tid] + redS[3][tid];
        int t2 = redQ[0][tid] + redQ[1][tid] + redQ[2][tid] + redQ[3][tid];
        atomicAdd(&ch_sum[tid], t1);
        atomicAdd(&ch_sumsq[tid], (unsigned long long)(long long)t2);
    }
}

// ---------------- kernel 4: fold BN stats + boundary corrections into per-channel affine
// A2[o] = -2*a ;  B2[f][o] = (576 - corr[f][o])*a + b  for edge-combo f (4 flag bits)
__global__ void bnprep_kernel(const int* __restrict__ ch_sum,
                              const unsigned long long* __restrict__ ch_sumsq,
                              const float* __restrict__ wscale,
                              const float* __restrict__ gamma,
                              const float* __restrict__ beta,
                              const uint64_t* __restrict__ wbits,
                              float* __restrict__ A2, float* __restrict__ B2) {
    int o = threadIdx.x;  // 64 threads
    double P = (double)NHW;
    double meanS = (double)ch_sum[o] / P;
    double e2 = (double)ch_sumsq[o] / P;
    double varS = e2 - meanS * meanS;
    double sc = (double)wscale[o];
    double mean_y = sc * meanS;
    double var_y = sc * sc * varS;
    double inv = (double)gamma[o] / sqrt(var_y + 1e-5);
    float a = (float)(sc * inv);
    float b = (float)((double)beta[o] - mean_y * inv);
    A2[o] = -2.0f * a;
    int tc[9];
#pragma unroll
    for (int t = 0; t < 9; t++) tc[t] = 64 - 2 * (int)__builtin_popcountll(wbits[o * 9 + t]);
#pragma unroll
    for (int f = 0; f < 16; f++) {
        int corr = 0;
#pragma unroll
        for (int t = 0; t < 9; t++) {
            int r = t / 3, c = t % 3;
            bool pad = ((f & 1) && r == 0) || ((f & 2) && r == 2) ||
                       ((f & 4) && c == 0) || ((f & 8) && c == 2);
            if (pad) corr += tc[t];
        }
        B2[f * 64 + o] = (float)(576 - corr) * a + b;
    }
}

// ---------------- kernel 5: conv + BN affine + residual; lane = pixel, loop over channels
// wave = 64 consecutive pixels of one image (196 waves/image, 6272 waves total)
__global__ __launch_bounds__(256) void final3_kernel(const uint64_t* __restrict__ bits,
                                                     const uint64_t* __restrict__ wbits,
                                                     const float* __restrict__ A2,
                                                     const float* __restrict__ B2,
                                                     const float* __restrict__ x,
                                                     float* __restrict__ out) {
    __shared__ float b2s[16][65];
    int tid = threadIdx.x;
    for (int e = tid; e < 16 * 64; e += 256) b2s[e >> 6][e & 63] = B2[e];
    __syncthreads();

    int wave = tid >> 6, lane = tid & 63;
    int Wid = blockIdx.x * 4 + wave;                  // < 6272 exact
    int n = __builtin_amdgcn_readfirstlane(Wid / 196);
    int p = (Wid - n * 196) * 64 + lane;              // pixel index within image, < 12544
    int h = p / WW;
    int w = p - h * WW;

    const uint64_t* bp = bits + (size_t)n * HW;
    uint64_t win[9];
#pragma unroll
    for (int t = 0; t < 9; t++) {
        int hh = h + (t / 3) - 1;
        int ww = w + (t % 3) - 1;
        bool valid = (hh >= 0) && (hh < HH) && (ww >= 0) && (ww < WW);
        int hc = hh < 0 ? 0 : (hh > HH - 1 ? HH - 1 : hh);
        int wc = ww < 0 ? 0 : (ww > WW - 1 ? WW - 1 : ww);
        uint64_t v = bp[hc * WW + wc];
        win[t] = valid ? v : 0ull;
    }
    int f = (h == 0 ? 1 : 0) | (h == HH - 1 ? 2 : 0) | (w == 0 ? 4 : 0) | (w == WW - 1 ? 8 : 0);
    const float* b2row = &b2s[f][0];

    const float* xb = x + (size_t)n * CC * HW;
    float* ob = out + (size_t)n * CC * HW;
    uint32_t idx = (uint32_t)p;
#pragma unroll 2
    for (int o = 0; o < 64; o++) {
        const uint64_t* wp = wbits + o * 9;   // wave-uniform -> scalar loads
        int pc0 = (int)__builtin_popcountll(win[0] ^ wp[0])
                + (int)__builtin_popcountll(win[1] ^ wp[1])
                + (int)__builtin_popcountll(win[2] ^ wp[2]);
        int pc1 = (int)__builtin_popcountll(win[3] ^ wp[3])
                + (int)__builtin_popcountll(win[4] ^ wp[4])
                + (int)__builtin_popcountll(win[5] ^ wp[5]);
        int pc2 = (int)__builtin_popcountll(win[6] ^ wp[6])
                + (int)__builtin_popcountll(win[7] ^ wp[7])
                + (int)__builtin_popcountll(win[8] ^ wp[8]);
        int pc = pc0 + pc1 + pc2;
        float y = fmaf((float)pc, A2[o], b2row[o]);
        ob[idx] = y + xb[idx];
        idx += HW;
    }
}

extern "C" void kernel_launch(void* const* d_in, const int* in_sizes, int n_in,
                              void* d_out, int out_size, void* d_ws, size_t ws_size,
                              hipStream_t stream) {
    const float* x     = (const float*)d_in[0];
    const float* wflat = (const float*)d_in[1];
    const float* gamma = (const float*)d_in[2];
    const float* beta  = (const float*)d_in[3];
    float* out = (float*)d_out;

    char* ws = (char*)d_ws;
    uint64_t* bits  = (uint64_t*)ws;                          // 401408*8 = 3,211,264 B
    uint64_t* wbits = (uint64_t*)(ws + 3211264);              // 576*8 = 4608 B
    float* wscale   = (float*)(ws + 3215872);                 // 256 B
    int* ch_sum     = (int*)(ws + 3216128);                   // 256 B
    unsigned long long* ch_sumsq = (unsigned long long*)(ws + 3216384); // 512 B
    float* A2       = (float*)(ws + 3216896);                 // 256 B
    float* B2       = (float*)(ws + 3217152);                 // 16*64*4 = 4096 B

    wpack_kernel<<<64, 64, 0, stream>>>(wflat, wbits, wscale, ch_sum, ch_sumsq);
    xpack2_kernel<<<NHW / 2 / 256, 256, 0, stream>>>(x, bits);
    stats3_kernel<<<NB * HH * 2 / 4, 256, 0, stream>>>(bits, wbits, ch_sum, ch_sumsq);
    bnprep_kernel<<<1, 64, 0, stream>>>(ch_sum, ch_sumsq, wscale, gamma, beta, wbits, A2, B2);
    final3_kernel<<<NB * HW / 64 / 4, 256, 0, stream>>>(bits, wbits, A2, B2, x, out);
}